// Round 3
// baseline (56.764 us; speedup 1.0000x reference)
//
#include <hip/hip_runtime.h>
#include <hip/hip_bf16.h>
#include <math.h>

// B=128, F_IN=1000, D=512, K=10, C=5, T=1000, TAU=0.1
// Contraction: logits_s[b,t,k] = sum_c v[b,c,t]*M[b,c,k], M = h @ W_mlp.
// 3 kernels: kA  (adapt k-split partials pA)
//            kBR (inline pA-reduce+bias+relu in LDS, channel d-split partials pB)
//            kCM (per-b: reduce pB -> h -> gate p[c], M[c][k] in regs; then
//                 per-(b,t) gumbel-sigmoid, softmax_c, MLP, softmax_k epilogue)

// ---- adapt partials: pA[s][b][e] ; s=10 splits of 100 k, 4 b per block ----
__global__ __launch_bounds__(256) void kA(const float* __restrict__ feats,
                                          const float* __restrict__ W_adapt,
                                          float* __restrict__ pA) {
    int b0 = blockIdx.x * 4;          // 32 b-tiles
    int s  = blockIdx.y;              // 10 k-splits
    int k0 = s * 100;
    int e  = threadIdx.x;             // and e+256
    float acc[4][2] = {};
    #pragma unroll 2
    for (int k = 0; k < 100; ++k) {
        const float* w = &W_adapt[(k0 + k) * 512 + e];
        float w0 = w[0], w1 = w[256];
        #pragma unroll
        for (int j = 0; j < 4; ++j) {
            float f = feats[(b0 + j) * 1000 + k0 + k];   // wave-uniform
            acc[j][0] = fmaf(f, w0, acc[j][0]);
            acc[j][1] = fmaf(f, w1, acc[j][1]);
        }
    }
    #pragma unroll
    for (int j = 0; j < 4; ++j) {
        pA[(s * 128 + b0 + j) * 512 + e]       = acc[j][0];
        pA[(s * 128 + b0 + j) * 512 + e + 256] = acc[j][1];
    }
}

// ---- channel partials with inline adapt-reduce ----
// block: (bt 16 x eh 2, s 4, c 5) = 640 blocks. LDS: r_b slice [8b][128d].
__global__ __launch_bounds__(256) void kBR(const float* __restrict__ pA,
                                           const float* __restrict__ b_adapt,
                                           const float* __restrict__ W_ch,
                                           float* __restrict__ pB) {
    __shared__ float lds_rb[1024];                   // [j=8][d=128]
    int bt = blockIdx.x >> 1, eh = blockIdx.x & 1;
    int s  = blockIdx.y;                             // 4 d-splits
    int c  = blockIdx.z;                             // 5
    int tid = threadIdx.x;
    int e  = eh * 256 + tid;
    int b0 = bt * 8, d0 = s * 128;

    // phase A: r_b[b0+j][d0+d] = relu(b_adapt + sum_s pA)
    #pragma unroll
    for (int i = 0; i < 4; ++i) {
        int idx = i * 256 + tid;
        int j = idx >> 7, d = idx & 127;
        float g = b_adapt[d0 + d];
        #pragma unroll
        for (int sp = 0; sp < 10; ++sp)
            g += pA[sp * 65536 + (b0 + j) * 512 + d0 + d];
        lds_rb[idx] = fmaxf(g, 0.f);
    }
    __syncthreads();

    // phase B: acc[j] = sum_d r_b[j][d] * W_ch[c][d0+d][e]
    const float* wb = &W_ch[((size_t)c * 512 + d0) * 512 + e];
    float acc[8] = {};
    #pragma unroll 4
    for (int d = 0; d < 128; ++d) {
        float w = wb[d * 512];
        #pragma unroll
        for (int j = 0; j < 8; ++j)
            acc[j] = fmaf(lds_rb[j * 128 + d], w, acc[j]);  // LDS broadcast
    }
    #pragma unroll
    for (int j = 0; j < 8; ++j)
        pB[((s * 5 + c) * 128 + b0 + j) * 512 + e] = acc[j];
}

// ---- mega epilogue: per (b, t-block) ----
// phase 1: wave wv owns c=wv (and wave0 also c=4): h = relu(b_ch + sum_s pB);
//          gate partial + M partials, shfl-reduce 11 vals, LDS broadcast.
// phase 2: per t: gumbel-sigmoid -> g_t, softmax_c -> v, lg = relu(v@M + b_mlp),
//          r_s = softmax_k(lg) -> (T,B,K).
__global__ __launch_bounds__(256) void kCM(const float* __restrict__ pB,
                                           const float* __restrict__ b_ch,
                                           const float* __restrict__ W_gate,
                                           const float* __restrict__ W_mlp,
                                           const float* __restrict__ b_gate,
                                           const float* __restrict__ b_mlp,
                                           const float* __restrict__ gumbel,
                                           float* __restrict__ out_rs,
                                           float* __restrict__ out_gt,
                                           float* __restrict__ out_pt) {
    __shared__ float red[5][12];
    int tid = threadIdx.x;
    int wv = tid >> 6, lane = tid & 63;
    int b = blockIdx.y;

    #pragma unroll
    for (int ci = 0; ci < 2; ++ci) {
        int c = wv + ci * 4;
        if (c <= 4) {
            float gs = 0.f, am[10] = {};
            #pragma unroll
            for (int i = 0; i < 8; ++i) {
                int e = i * 64 + lane;
                float hs = b_ch[c * 512 + e];
                #pragma unroll
                for (int sp = 0; sp < 4; ++sp)
                    hs += pB[((sp * 5 + c) * 128 + b) * 512 + e];
                float h = fmaxf(hs, 0.f);
                gs = fmaf(h, W_gate[c * 512 + e], gs);
                const float* wm = &W_mlp[e * 10];
                #pragma unroll
                for (int k = 0; k < 10; ++k) am[k] = fmaf(h, wm[k], am[k]);
            }
            #pragma unroll
            for (int off = 32; off; off >>= 1) {
                gs += __shfl_xor(gs, off);
                #pragma unroll
                for (int k = 0; k < 10; ++k) am[k] += __shfl_xor(am[k], off);
            }
            if (lane == 0) {
                red[c][0] = gs;
                #pragma unroll
                for (int k = 0; k < 10; ++k) red[c][1 + k] = am[k];
            }
        }
    }
    __syncthreads();

    float pv[5], Mv[5][10];
    #pragma unroll
    for (int c = 0; c < 5; ++c) {
        pv[c] = 1.f / (1.f + __expf(-(red[c][0] + b_gate[c])));
        #pragma unroll
        for (int k = 0; k < 10; ++k) Mv[c][k] = red[c][1 + k];
    }
    if (blockIdx.x == 0 && tid == 0) {
        #pragma unroll
        for (int c = 0; c < 5; ++c) out_pt[b * 5 + c] = pv[c];
    }

    int t = blockIdx.x * 256 + tid;
    if (t >= 1000) return;
    float ex[5], ssum = 0.f;
    #pragma unroll
    for (int c = 0; c < 5; ++c) {
        float2 gu = *(const float2*)&gumbel[(size_t)(((b * 5 + c) * 1000) + t) * 2];
        float arg = (2.f * pv[c] - 1.f + gu.y - gu.x) * 10.0f;  // /tau
        float gt  = 1.f / (1.f + __expf(-arg));
        out_gt[(b * 5 + c) * 1000 + t] = gt;
        float e = __expf(gt);
        ex[c] = e; ssum += e;
    }
    float inv = 1.f / ssum;
    float lg[10];
    #pragma unroll
    for (int k = 0; k < 10; ++k) lg[k] = b_mlp[k];
    #pragma unroll
    for (int c = 0; c < 5; ++c) {
        float v = ex[c] * inv;
        #pragma unroll
        for (int k = 0; k < 10; ++k) lg[k] = fmaf(v, Mv[c][k], lg[k]);
    }
    float mx = 0.f;
    #pragma unroll
    for (int k = 0; k < 10; ++k) { lg[k] = fmaxf(lg[k], 0.f); mx = fmaxf(mx, lg[k]); }
    float se = 0.f;
    #pragma unroll
    for (int k = 0; k < 10; ++k) { lg[k] = __expf(lg[k] - mx); se += lg[k]; }
    float invs = 1.f / se;
    float2 outv[5];
    #pragma unroll
    for (int k = 0; k < 10; ++k) ((float*)outv)[k] = lg[k] * invs;
    float2* dst = (float2*)&out_rs[(size_t)t * 1280 + b * 10];
    #pragma unroll
    for (int j = 0; j < 5; ++j) dst[j] = outv[j];
}

extern "C" void kernel_launch(void* const* d_in, const int* in_sizes, int n_in,
                              void* d_out, int out_size, void* d_ws, size_t ws_size,
                              hipStream_t stream) {
    const float* feats   = (const float*)d_in[0];
    const float* W_adapt = (const float*)d_in[1];
    const float* b_adapt = (const float*)d_in[2];
    const float* W_ch    = (const float*)d_in[3];
    const float* b_ch    = (const float*)d_in[4];
    const float* W_gate  = (const float*)d_in[5];
    const float* b_gate  = (const float*)d_in[6];
    const float* W_mlp   = (const float*)d_in[7];
    const float* b_mlp   = (const float*)d_in[8];
    const float* gumbel  = (const float*)d_in[9];

    float* out    = (float*)d_out;
    float* out_rs = out;                  // (T,B,K)  1,280,000
    float* out_gt = out + 1280000;        // (B,C,T)    640,000
    float* out_pt = out + 1920000;        // (B,C,1)        640

    float* ws = (float*)d_ws;
    float* pA = ws;                       // 10*128*512  = 655,360
    float* pB = pA + 655360;              // 4*5*128*512 = 1,310,720

    kA <<<dim3(32, 10),   256, 0, stream>>>(feats, W_adapt, pA);
    kBR<<<dim3(32, 4, 5), 256, 0, stream>>>(pA, b_adapt, W_ch, pB);
    kCM<<<dim3(4, 128),   256, 0, stream>>>(pB, b_ch, W_gate, W_mlp, b_gate,
                                            b_mlp, gumbel, out_rs, out_gt, out_pt);
}